// Round 1
// baseline (826.400 us; speedup 1.0000x reference)
//
#include <hip/hip_runtime.h>
#include <hip/hip_bf16.h>

// Sizes (fixed by the problem)
#define NATOMS 131072
#define NBLK   8192
#define HDIM   256
#define NHEAD  8
#define TDIM   336   // 320 aug dims + 1 (ck_b . Q) + pad

typedef __attribute__((ext_vector_type(8))) short short8;
typedef __attribute__((ext_vector_type(4))) float floatx4;

__device__ __forceinline__ float bfu2f(unsigned short u) {
  unsigned int v = ((unsigned int)u) << 16;
  return __builtin_bit_cast(float, v);
}
__device__ __forceinline__ unsigned short f2bfu(float f) {
  unsigned int u = __builtin_bit_cast(unsigned int, f);
  u += 0x7fffu + ((u >> 16) & 1u);
  return (unsigned short)(u >> 16);
}

// ---------------- K0: q = seed@Wq+bq ; A_sc[c][h] = scale * Wk[c, h*32+d] . q[h*32+d] ; sb[h]
__global__ __launch_bounds__(256) void k0_prep(const float* __restrict__ seed,
    const float* __restrict__ Wq, const float* __restrict__ bq,
    const float* __restrict__ Wk, const float* __restrict__ bk,
    float* __restrict__ A_sc, float* __restrict__ sb) {
  __shared__ float qls[256];
  int t = threadIdx.x;
  float acc = bq[t];
  for (int c = 0; c < 256; ++c) acc += seed[c] * Wq[c * 256 + t];
  qls[t] = acc;
  __syncthreads();
  const float scale = 0.17677669529663687f;  // 1/sqrt(32)
  for (int m = 0; m < 8; ++m) {
    int o = t + 256 * m;
    int c = o >> 3, h = o & 7;
    float a = 0.f;
    for (int d = 0; d < 32; ++d) a += Wk[c * 256 + h * 32 + d] * qls[h * 32 + d];
    A_sc[o] = a * scale;
  }
  if (t < 8) {
    float a = 0.f;
    for (int d = 0; d < 32; ++d) a += bk[t * 32 + d] * qls[t * 32 + d];
    sb[t] = a * scale;
  }
}

// ---------------- Kp1: M[i][c] = cq_w[i,:] . ckT[:,c]  (ckT[j][c]=ck_w[c][j], col 320 = ck_b)
__global__ __launch_bounds__(352) void kp1(const float* __restrict__ cq_w,
    const float* __restrict__ cq_b, const float* __restrict__ ck_w,
    const float* __restrict__ ck_b, float* __restrict__ M, float* __restrict__ vbias) {
  __shared__ float row[256];
  int i = blockIdx.x, t = threadIdx.x;
  if (t < 256) row[t] = cq_w[i * 256 + t];
  __syncthreads();
  if (t < TDIM) {
    float a = 0.f;
    if (t < 320) { const float* w = ck_w + t * 256; for (int j = 0; j < 256; ++j) a += row[j] * w[j]; }
    else if (t == 320) { for (int j = 0; j < 256; ++j) a += row[j] * ck_b[j]; }
    M[i * TDIM + t] = a;
  }
  if (i == 0) {
    __syncthreads();
    if (t < 256) row[t] = cq_b[t];
    __syncthreads();
    if (t < TDIM) {
      float a = 0.f;
      if (t < 320) { const float* w = ck_w + t * 256; for (int j = 0; j < 256; ++j) a += row[j] * w[j]; }
      else if (t == 320) { for (int j = 0; j < 256; ++j) a += row[j] * ck_b[j]; }
      vbias[t] = a;
    }
  }
}

// ---------------- Kp2: MM[p][c] = Wo[p,:] . M[:,c] ; block 256: vb2[c] = bo.M[:,c] + vbias[c]
__global__ __launch_bounds__(352) void kp2(const float* __restrict__ Wo,
    const float* __restrict__ bo, const float* __restrict__ M,
    const float* __restrict__ vbias, float* __restrict__ MM, float* __restrict__ vb2) {
  __shared__ float row[256];
  int p = blockIdx.x, t = threadIdx.x;
  const float* src = (p < 256) ? (Wo + p * 256) : bo;
  if (t < 256) row[t] = src[t];
  __syncthreads();
  if (t < TDIM) {
    float a = 0.f;
    for (int i = 0; i < 256; ++i) a += row[i] * M[i * TDIM + t];
    if (p < 256) MM[p * TDIM + t] = a;
    else vb2[t] = a + vbias[t];
  }
}

// ---------------- Kp3: CV1[k][j] = cv_w[k,:] . cmlp_w1[:,j] ; block 320: cb1 = cv_b@w1m + b1m
__global__ __launch_bounds__(256) void kp3(const float* __restrict__ cv_w,
    const float* __restrict__ cv_b, const float* __restrict__ w1m,
    const float* __restrict__ b1m, float* __restrict__ CV1, float* __restrict__ cb1) {
  __shared__ float row[256];
  int k = blockIdx.x, t = threadIdx.x;
  const float* src = (k < 320) ? (cv_w + k * 256) : cv_b;
  row[t] = src[t];
  __syncthreads();
  float a = 0.f;
  for (int i = 0; i < 256; ++i) a += row[i] * w1m[i * 256 + t];
  if (k < 320) CV1[k * 256 + t] = a;
  else cb1[t] = a + b1m[t];
}

// ---------------- Kcast: W1t[n][k] = bf16(ffn_w1[k][n]) (512x256), W2t[n][k] = bf16(ffn_w2[k][n]) (256x512)
__global__ __launch_bounds__(256) void kcast(const float* __restrict__ fw1,
    const float* __restrict__ fw2, unsigned short* __restrict__ W1t,
    unsigned short* __restrict__ W2t) {
  int b = blockIdx.x, t = threadIdx.x;
  if (b < 512) {
    W1t[b * 256 + t] = f2bfu(fw1[t * 512 + b]);
  } else {
    int n = b - 512;
    for (int m = 0; m < 2; ++m) {
      int k = t + 256 * m;
      W2t[n * 512 + k] = f2bfu(fw2[k * 256 + n]);
    }
  }
}

// ---------------- KG1: PMA scores + softmax + per-head weighted sums y (4 blocks / wg)
__global__ __launch_bounds__(256) void kg1(const float* __restrict__ x,
    const float* __restrict__ A_sc, const float* __restrict__ sb,
    unsigned short* __restrict__ y_bf) {
  __shared__ unsigned short xs[64][264];
  __shared__ float Als[2048];
  __shared__ float sbl[8];
  __shared__ float s_l[64][8];
  __shared__ float w_l[64][8];
  int t = threadIdx.x, wg = blockIdx.x;
  long a0 = (long)wg * 64;
  const float4* x4 = (const float4*)(x + a0 * 256);
  for (int m = 0; m < 16; ++m) {
    int f4 = t + 256 * m;
    int row = f4 >> 6, c4 = f4 & 63;
    float4 v = x4[f4];
    ushort4 u;
    u.x = f2bfu(v.x); u.y = f2bfu(v.y); u.z = f2bfu(v.z); u.w = f2bfu(v.w);
    *(ushort4*)&xs[row][c4 * 4] = u;
  }
  for (int m = 0; m < 8; ++m) Als[t + 256 * m] = A_sc[t + 256 * m];
  if (t < 8) sbl[t] = sb[t];
  __syncthreads();
  for (int m = 0; m < 2; ++m) {
    int o = t + 256 * m;
    int i = o >> 3, h = o & 7;
    float a = sbl[h];
    for (int c = 0; c < 256; ++c) a += bfu2f(xs[i][c]) * Als[c * 8 + h];
    s_l[i][h] = a;
  }
  __syncthreads();
  if (t < 32) {
    int b = t >> 3, h = t & 7;
    float mx = -1e30f;
    for (int i = 0; i < 16; ++i) mx = fmaxf(mx, s_l[b * 16 + i][h]);
    float se = 0.f;
    for (int i = 0; i < 16; ++i) se += __expf(s_l[b * 16 + i][h] - mx);
    float inv = 1.f / fmaxf(se, 1e-20f);
    for (int i = 0; i < 16; ++i) w_l[b * 16 + i][h] = __expf(s_l[b * 16 + i][h] - mx) * inv;
  }
  __syncthreads();
  float yacc[32];
  for (int k = 0; k < 32; ++k) yacc[k] = 0.f;
  for (int b = 0; b < 4; ++b)
    for (int i = 0; i < 16; ++i) {
      float xv = bfu2f(xs[b * 16 + i][t]);
      for (int h = 0; h < 8; ++h) yacc[b * 8 + h] += w_l[b * 16 + i][h] * xv;
    }
  for (int b = 0; b < 4; ++b)
    for (int h = 0; h < 8; ++h)
      y_bf[((long)(wg * 4 + b) * 8 + h) * 256 + t] = f2bfu(yacc[b * 8 + h]);
}

// ---------------- G2: BP[b][j] = y[b][j>>5] . Wv[:,j] + bv[j]   (16 blocks / wg)
__global__ __launch_bounds__(256) void g2k(const unsigned short* __restrict__ y_bf,
    const float* __restrict__ Wv, const float* __restrict__ bv,
    unsigned short* __restrict__ BP_bf) {
  __shared__ unsigned short ys[8][8][264];
  int t = threadIdx.x;
  int B0 = blockIdx.x * 16;
  int h = t >> 5;
  float bvj = bv[t];
  for (int g = 0; g < 2; ++g) {
    __syncthreads();
    for (int m = 0; m < 8; ++m) {
      int flat = (t + 256 * m) * 8;
      int bb = flat >> 11, rem = flat & 2047;
      int hh = rem >> 8, c = rem & 255;
      short8 v = *(const short8*)(y_bf + ((long)(B0 + g * 8 + bb) * 8 + hh) * 256 + c);
      *(short8*)&ys[bb][hh][c] = v;
    }
    __syncthreads();
    float acc[8];
    for (int bb = 0; bb < 8; ++bb) acc[bb] = bvj;
    for (int c = 0; c < 256; ++c) {
      float w = Wv[c * 256 + t];
      for (int bb = 0; bb < 8; ++bb) acc[bb] += w * bfu2f(ys[bb][h][c]);
    }
    for (int bb = 0; bb < 8; ++bb)
      BP_bf[(long)(B0 + g * 8 + bb) * 256 + t] = f2bfu(acc[bb]);
  }
}

// ---------------- Gb1: T[b][c] = BP[b,:] . MM[:,c] + vb2[c]   (16 blocks / wg)
__global__ __launch_bounds__(256) void gb1(const unsigned short* __restrict__ BP_bf,
    const float* __restrict__ MM, const float* __restrict__ vb2, float* __restrict__ T) {
  __shared__ float rb[16][257];
  int t = threadIdx.x;
  int B0 = blockIdx.x * 16;
  for (int m = 0; m < 16; ++m) {
    int flat = t + 256 * m;
    int r = flat >> 8, c = flat & 255;
    rb[r][c] = bfu2f(BP_bf[(long)(B0 + r) * 256 + c]);
  }
  __syncthreads();
  for (int chunk = 0; chunk < 2; ++chunk) {
    int c = chunk * 256 + t;
    if (c < TDIM) {
      float vb = vb2[c];
      for (int g = 0; g < 2; ++g) {
        float acc[8];
        for (int bb = 0; bb < 8; ++bb) acc[bb] = vb;
        for (int j = 0; j < 256; ++j) {
          float w = MM[j * TDIM + c];
          for (int bb = 0; bb < 8; ++bb) acc[bb] += w * rb[g * 8 + bb][j];
        }
        for (int bb = 0; bb < 8; ++bb) T[(long)(B0 + g * 8 + bb) * TDIM + c] = acc[bb];
      }
    }
  }
}

// ---------------- KG3: geometry + cross-attn scores + softmax + z (4 blocks / wg)
__global__ __launch_bounds__(256) void kg3(const float* __restrict__ x,
    const float* __restrict__ pos, const float* __restrict__ T,
    const float* __restrict__ centers, const float* __restrict__ widths,
    const float* __restrict__ geom_w, const float* __restrict__ geom_b,
    unsigned short* __restrict__ z_bf) {
  __shared__ unsigned short xs[64][264];
  __shared__ float rbfp[64][65];
  __shared__ float rbfl[64][17];
  __shared__ float Tls[4][352];
  __shared__ float ps[64][3];
  __shared__ float cent[4][3];
  __shared__ float ctr[16], wid[16];
  __shared__ float scl[64], w2l[64];
  int t = threadIdx.x, wg = blockIdx.x;
  long a0 = (long)wg * 64;
  int b0 = wg * 4;
  const float4* x4 = (const float4*)(x + a0 * 256);
  for (int m = 0; m < 16; ++m) {
    int f4 = t + 256 * m;
    int row = f4 >> 6, c4 = f4 & 63;
    float4 v = x4[f4];
    ushort4 u;
    u.x = f2bfu(v.x); u.y = f2bfu(v.y); u.z = f2bfu(v.z); u.w = f2bfu(v.w);
    *(ushort4*)&xs[row][c4 * 4] = u;
  }
  if (t < 192) ps[t / 3][t % 3] = pos[a0 * 3 + t];
  if (t >= 224 && t < 240) ctr[t - 224] = centers[t - 224];
  if (t >= 240) wid[t - 240] = widths[t - 240];
  for (int b = 0; b < 4; ++b) {
    Tls[b][t] = T[(long)(b0 + b) * TDIM + t];
    if (t < 80) Tls[b][256 + t] = T[(long)(b0 + b) * TDIM + 256 + t];
  }
  __syncthreads();
  if (t < 12) {
    int b = t / 3, d = t % 3;
    float s = 0.f;
    for (int i = 0; i < 16; ++i) s += ps[b * 16 + i][d];
    cent[b][d] = s * 0.0625f;
  }
  __syncthreads();
  if (t < 64) {
    int b = t >> 4;
    float dx = ps[t][0] - cent[b][0];
    float dy = ps[t][1] - cent[b][1];
    float dz = ps[t][2] - cent[b][2];
    float dist = sqrtf(dx * dx + dy * dy + dz * dz);
    for (int r = 0; r < 16; ++r) {
      float dd = dist - ctr[r];
      rbfl[t][r] = __expf(-dd * dd / (2.f * wid[r] * wid[r]));
    }
  }
  __syncthreads();
  {
    int i = t >> 2, q0 = (t & 3) * 16;
    for (int q = q0; q < q0 + 16; ++q) {
      float a = geom_b[q];
      for (int r = 0; r < 16; ++r) a += rbfl[i][r] * geom_w[r * 64 + q];
      rbfp[i][q] = a;
    }
  }
  __syncthreads();
  {
    int i = t >> 2, p = t & 3, b = i >> 4;
    float a = 0.f;
    for (int c = p * 64; c < p * 64 + 64; ++c) a += bfu2f(xs[i][c]) * Tls[b][c];
    for (int q = p * 16; q < p * 16 + 16; ++q) a += rbfp[i][q] * Tls[b][256 + q];
    a += __shfl_xor(a, 1);
    a += __shfl_xor(a, 2);
    float sc = (a + Tls[b][320]) * 0.0625f;  // / sqrt(256)
    if (p == 0) scl[i] = sc;
  }
  __syncthreads();
  if (t < 4) {
    float mx = -1e30f;
    for (int i = 0; i < 16; ++i) mx = fmaxf(mx, scl[t * 16 + i]);
    float se = 0.f;
    for (int i = 0; i < 16; ++i) se += __expf(scl[t * 16 + i] - mx);
    float inv = 1.f / fmaxf(se, 1e-20f);
    for (int i = 0; i < 16; ++i) w2l[t * 16 + i] = __expf(scl[t * 16 + i] - mx) * inv;
  }
  __syncthreads();
  for (int b = 0; b < 4; ++b) {
    float zv = 0.f;
    for (int i = 0; i < 16; ++i) zv += w2l[b * 16 + i] * bfu2f(xs[b * 16 + i][t]);
    z_bf[(long)(b0 + b) * 320 + t] = f2bfu(zv);
  }
  {
    int q = t & 63, b = t >> 6;
    float zq = 0.f;
    for (int i = 0; i < 16; ++i) zq += w2l[b * 16 + i] * rbfp[b * 16 + i][q];
    z_bf[(long)(b0 + b) * 320 + 256 + q] = f2bfu(zq);
  }
}

// ---------------- Gb2: upd = relu(z@CV1+cb1)@cmlp_w2 + cmlp_b2   (16 blocks / wg)
__global__ __launch_bounds__(256) void gb2(const unsigned short* __restrict__ z_bf,
    const float* __restrict__ CV1, const float* __restrict__ cb1,
    const float* __restrict__ W2m, const float* __restrict__ b2m,
    float* __restrict__ upd) {
  __shared__ float zrb[16][321];
  __shared__ float prb[16][257];
  int t = threadIdx.x;
  int B0 = blockIdx.x * 16;
  for (int m = 0; m < 20; ++m) {
    int flat = t + 256 * m;
    int r = flat / 320, c = flat - r * 320;
    zrb[r][c] = bfu2f(z_bf[(long)(B0 + r) * 320 + c]);
  }
  __syncthreads();
  float cb = cb1[t];
  for (int g = 0; g < 2; ++g) {
    float acc[8];
    for (int bb = 0; bb < 8; ++bb) acc[bb] = cb;
    for (int k = 0; k < 320; ++k) {
      float w = CV1[k * 256 + t];
      for (int bb = 0; bb < 8; ++bb) acc[bb] += w * zrb[g * 8 + bb][k];
    }
    for (int bb = 0; bb < 8; ++bb) prb[g * 8 + bb][t] = fmaxf(acc[bb], 0.f);
  }
  __syncthreads();
  float b2 = b2m[t];
  for (int g = 0; g < 2; ++g) {
    float acc[8];
    for (int bb = 0; bb < 8; ++bb) acc[bb] = b2;
    for (int k = 0; k < 256; ++k) {
      float w = W2m[k * 256 + t];
      for (int bb = 0; bb < 8; ++bb) acc[bb] += w * prb[g * 8 + bb][k];
    }
    for (int bb = 0; bb < 8; ++bb) upd[(long)(B0 + g * 8 + bb) * 256 + t] = acc[bb];
  }
}

// ---------------- KF: LN1 + FFN (bf16 MFMA) + residual + LN2  (64 atoms / wg, 4 waves)
__global__ __launch_bounds__(256) void kf(const float* __restrict__ x,
    const float* __restrict__ upd, const unsigned short* __restrict__ W1t,
    const unsigned short* __restrict__ W2t, const float* __restrict__ b1,
    const float* __restrict__ b2, const float* __restrict__ g1,
    const float* __restrict__ be1, const float* __restrict__ g2,
    const float* __restrict__ be2, float* __restrict__ out) {
  __shared__ unsigned short x1s[64][280];  // stride 560B: 16B aligned, 2-way-bank frags
  __shared__ unsigned short hs[64][72];    // stride 144B
  __shared__ float updl[4][256];
  int t = threadIdx.x, wg = blockIdx.x;
  long a0 = (long)wg * 64;
  int b0 = wg * 4;
  for (int m = 0; m < 4; ++m) {
    int flat = t + 256 * m;
    int r = flat >> 8, c = flat & 255;
    updl[r][c] = upd[(long)(b0 + r) * 256 + c];
  }
  __syncthreads();
  int r = t >> 2, p = t & 3;
  {
    const float4* xr = (const float4*)(x + (a0 + r) * 256 + p * 64);
    const float* ur = &updl[r >> 4][p * 64];
    float s = 0.f, sq = 0.f;
    float4 vv[16];
    for (int m = 0; m < 16; ++m) {
      float4 v = xr[m];
      v.x += ur[m * 4 + 0]; v.y += ur[m * 4 + 1];
      v.z += ur[m * 4 + 2]; v.w += ur[m * 4 + 3];
      vv[m] = v;
      s += v.x + v.y + v.z + v.w;
      sq += v.x * v.x + v.y * v.y + v.z * v.z + v.w * v.w;
    }
    s += __shfl_xor(s, 1); s += __shfl_xor(s, 2);
    sq += __shfl_xor(sq, 1); sq += __shfl_xor(sq, 2);
    float mu = s * (1.f / 256.f);
    float var = sq * (1.f / 256.f) - mu * mu;
    float rstd = rsqrtf(fmaxf(var, 0.f) + 1e-5f);
    for (int m = 0; m < 16; ++m) {
      float4 v = vv[m];
      float4 gv = ((const float4*)g1)[p * 16 + m];
      float4 bv = ((const float4*)be1)[p * 16 + m];
      ushort4 u;
      u.x = f2bfu((v.x - mu) * rstd * gv.x + bv.x);
      u.y = f2bfu((v.y - mu) * rstd * gv.y + bv.y);
      u.z = f2bfu((v.z - mu) * rstd * gv.z + bv.z);
      u.w = f2bfu((v.w - mu) * rstd * gv.w + bv.w);
      *(ushort4*)&x1s[r][p * 64 + m * 4] = u;
    }
  }
  __syncthreads();
  int lane = t & 63, w = t >> 6;
  int lrow = lane & 15, lk = (lane >> 4) * 8;
  floatx4 zero = {0.f, 0.f, 0.f, 0.f};
  floatx4 acc2[4][4];
  for (int rb = 0; rb < 4; ++rb)
    for (int cb = 0; cb < 4; ++cb) acc2[rb][cb] = zero;
  for (int s = 0; s < 8; ++s) {
    floatx4 acc1[4] = {zero, zero, zero, zero};
    int bcol = s * 64 + w * 16 + lrow;
    const short8* wp = (const short8*)(W1t + bcol * 256 + lk);
#pragma unroll
    for (int k0 = 0; k0 < 8; ++k0) {
      short8 bf = wp[k0 * 4];
      short8 af0 = *(const short8*)&x1s[0 * 16 + lrow][k0 * 32 + lk];
      short8 af1 = *(const short8*)&x1s[1 * 16 + lrow][k0 * 32 + lk];
      short8 af2 = *(const short8*)&x1s[2 * 16 + lrow][k0 * 32 + lk];
      short8 af3 = *(const short8*)&x1s[3 * 16 + lrow][k0 * 32 + lk];
      acc1[0] = __builtin_amdgcn_mfma_f32_16x16x32_bf16(af0, bf, acc1[0], 0, 0, 0);
      acc1[1] = __builtin_amdgcn_mfma_f32_16x16x32_bf16(af1, bf, acc1[1], 0, 0, 0);
      acc1[2] = __builtin_amdgcn_mfma_f32_16x16x32_bf16(af2, bf, acc1[2], 0, 0, 0);
      acc1[3] = __builtin_amdgcn_mfma_f32_16x16x32_bf16(af3, bf, acc1[3], 0, 0, 0);
    }
    float bias1 = b1[s * 64 + w * 16 + lrow];
    __syncthreads();  // previous GEMM2 finished reading hs
#pragma unroll
    for (int rb = 0; rb < 4; ++rb)
      for (int i = 0; i < 4; ++i) {
        float v = fmaxf(acc1[rb][i] + bias1, 0.f);
        hs[rb * 16 + (lane >> 4) * 4 + i][w * 16 + lrow] = f2bfu(v);
      }
    __syncthreads();
#pragma unroll
    for (int ks = 0; ks < 2; ++ks) {
      short8 a2[4];
      for (int rb = 0; rb < 4; ++rb)
        a2[rb] = *(const short8*)&hs[rb * 16 + lrow][ks * 32 + lk];
      for (int cb = 0; cb < 4; ++cb) {
        int col = w * 64 + cb * 16 + lrow;
        short8 b2f = *(const short8*)(W2t + col * 512 + s * 64 + ks * 32 + lk);
        for (int rb = 0; rb < 4; ++rb)
          acc2[rb][cb] = __builtin_amdgcn_mfma_f32_16x16x32_bf16(a2[rb], b2f, acc2[rb][cb], 0, 0, 0);
      }
    }
  }
  // epilogue: residual (bf16 x1) + bias2, in-place into x1s
  for (int cb = 0; cb < 4; ++cb) {
    int col = w * 64 + cb * 16 + lrow;
    float b2v = b2[col];
    for (int rb = 0; rb < 4; ++rb)
      for (int i = 0; i < 4; ++i) {
        int row = rb * 16 + (lane >> 4) * 4 + i;
        float res = acc2[rb][cb][i] + b2v + bfu2f(x1s[row][col]);
        x1s[row][col] = f2bfu(res);
      }
  }
  __syncthreads();
  // LN2 + store
  {
    float s = 0.f, sq = 0.f;
    for (int m = 0; m < 64; ++m) {
      float v = bfu2f(x1s[r][p * 64 + m]);
      s += v; sq += v * v;
    }
    s += __shfl_xor(s, 1); s += __shfl_xor(s, 2);
    sq += __shfl_xor(sq, 1); sq += __shfl_xor(sq, 2);
    float mu = s * (1.f / 256.f);
    float var = sq * (1.f / 256.f) - mu * mu;
    float rstd = rsqrtf(fmaxf(var, 0.f) + 1e-5f);
    float4* orow = (float4*)(out + (a0 + r) * 256 + p * 64);
    for (int m = 0; m < 16; ++m) {
      float4 gv = ((const float4*)g2)[p * 16 + m];
      float4 bv = ((const float4*)be2)[p * 16 + m];
      float4 o;
      o.x = (bfu2f(x1s[r][p * 64 + m * 4 + 0]) - mu) * rstd * gv.x + bv.x;
      o.y = (bfu2f(x1s[r][p * 64 + m * 4 + 1]) - mu) * rstd * gv.y + bv.y;
      o.z = (bfu2f(x1s[r][p * 64 + m * 4 + 2]) - mu) * rstd * gv.z + bv.z;
      o.w = (bfu2f(x1s[r][p * 64 + m * 4 + 3]) - mu) * rstd * gv.w + bv.w;
      orow[m] = o;
    }
  }
}

extern "C" void kernel_launch(void* const* d_in, const int* in_sizes, int n_in,
                              void* d_out, int out_size, void* d_ws, size_t ws_size,
                              hipStream_t stream) {
  (void)in_sizes; (void)n_in; (void)out_size; (void)ws_size;
  const float* x    = (const float*)d_in[0];
  const float* pos  = (const float*)d_in[1];
  const float* seed = (const float*)d_in[4];
  const float* Wq   = (const float*)d_in[5];
  const float* bq   = (const float*)d_in[6];
  const float* Wk   = (const float*)d_in[7];
  const float* bk   = (const float*)d_in[8];
  const float* Wv   = (const float*)d_in[9];
  const float* bv   = (const float*)d_in[10];
  const float* Wo   = (const float*)d_in[11];
  const float* bo   = (const float*)d_in[12];
  const float* centers = (const float*)d_in[13];
  const float* widths  = (const float*)d_in[14];
  const float* geom_w  = (const float*)d_in[15];
  const float* geom_b  = (const float*)d_in[16];
  const float* cq_w = (const float*)d_in[17];
  const float* cq_b = (const float*)d_in[18];
  const float* ck_w = (const float*)d_in[19];
  const float* ck_b = (const float*)d_in[20];
  const float* cv_w = (const float*)d_in[21];
  const float* cv_b = (const float*)d_in[22];
  const float* w1m  = (const float*)d_in[23];
  const float* b1m  = (const float*)d_in[24];
  const float* w2m  = (const float*)d_in[25];
  const float* b2m  = (const float*)d_in[26];
  const float* fw1  = (const float*)d_in[27];
  const float* fb1  = (const float*)d_in[28];
  const float* fw2  = (const float*)d_in[29];
  const float* fb2  = (const float*)d_in[30];
  const float* g1   = (const float*)d_in[31];
  const float* be1  = (const float*)d_in[32];
  const float* g2   = (const float*)d_in[33];
  const float* be2  = (const float*)d_in[34];

  float* ws = (float*)d_ws;
  float* A_sc  = ws + 0;        // 2048
  float* sb    = ws + 2048;     // 64
  float* M     = ws + 2112;     // 256*336
  float* vbias = ws + 88128;    // 352
  float* MM    = ws + 88480;    // 256*336
  float* vb2   = ws + 174496;   // 352
  float* CV1   = ws + 174848;   // 320*256
  float* cb1   = ws + 256768;   // 256
  unsigned short* W1t = (unsigned short*)(ws + 257024);   // 512*256 bf16
  unsigned short* W2t = (unsigned short*)(ws + 322560);   // 256*512 bf16
  unsigned short* BP  = (unsigned short*)(ws + 388096);   // 8192*256 bf16
  unsigned short* zbf = (unsigned short*)(ws + 1436672);  // 8192*320 bf16
  float* updw = ws + 2747392;                             // 8192*256 f32
  // total ws use: ~19.4 MB

  float* outp = (float*)d_out;
  unsigned short* ybf = (unsigned short*)d_out;  // scratch in d_out: 8192*8*256 bf16 (33.5MB)
  float* T = outp + 16777216;                    // scratch in d_out: 8192*336 f32 (11MB)

  k0_prep<<<dim3(1), dim3(256), 0, stream>>>(seed, Wq, bq, Wk, bk, A_sc, sb);
  kp1<<<dim3(256), dim3(352), 0, stream>>>(cq_w, cq_b, ck_w, ck_b, M, vbias);
  kp2<<<dim3(257), dim3(352), 0, stream>>>(Wo, bo, M, vbias, MM, vb2);
  kp3<<<dim3(321), dim3(256), 0, stream>>>(cv_w, cv_b, w1m, b1m, CV1, cb1);
  kcast<<<dim3(768), dim3(256), 0, stream>>>(fw1, fw2, W1t, W2t);
  kg1<<<dim3(2048), dim3(256), 0, stream>>>(x, A_sc, sb, ybf);
  g2k<<<dim3(512), dim3(256), 0, stream>>>(ybf, Wv, bv, BP);
  gb1<<<dim3(512), dim3(256), 0, stream>>>(BP, MM, vb2, T);
  kg3<<<dim3(2048), dim3(256), 0, stream>>>(x, pos, T, centers, widths, geom_w, geom_b, zbf);
  gb2<<<dim3(512), dim3(256), 0, stream>>>(zbf, CV1, cb1, w2m, b2m, updw);
  kf<<<dim3(2048), dim3(256), 0, stream>>>(x, updw, W1t, W2t, fb1, fb2, g1, be1, g2, be2, outp);
}

// Round 2
// 752.165 us; speedup vs baseline: 1.0987x; 1.0987x over previous
//
#include <hip/hip_runtime.h>
#include <hip/hip_bf16.h>

// Sizes (fixed by the problem)
#define NATOMS 131072
#define NBLK   8192
#define HDIM   256
#define NHEAD  8
#define TDIM   336   // 320 aug dims + 1 (ck_b . Q) + pad

typedef __attribute__((ext_vector_type(8))) short short8;
typedef __attribute__((ext_vector_type(4))) float floatx4;

__device__ __forceinline__ float bfu2f(unsigned short u) {
  unsigned int v = ((unsigned int)u) << 16;
  return __builtin_bit_cast(float, v);
}
__device__ __forceinline__ unsigned short f2bfu(float f) {
  unsigned int u = __builtin_bit_cast(unsigned int, f);
  u += 0x7fffu + ((u >> 16) & 1u);
  return (unsigned short)(u >> 16);
}

// ---------------- K0: q = seed@Wq+bq ; A_sc[c][h] = scale * Wk[c, h*32+d] . q[h*32+d] ; sb[h]
__global__ __launch_bounds__(256) void k0_prep(const float* __restrict__ seed,
    const float* __restrict__ Wq, const float* __restrict__ bq,
    const float* __restrict__ Wk, const float* __restrict__ bk,
    float* __restrict__ A_sc, float* __restrict__ sb) {
  __shared__ float qls[256];
  int t = threadIdx.x;
  float acc = bq[t];
  for (int c = 0; c < 256; ++c) acc += seed[c] * Wq[c * 256 + t];
  qls[t] = acc;
  __syncthreads();
  const float scale = 0.17677669529663687f;  // 1/sqrt(32)
  for (int m = 0; m < 8; ++m) {
    int o = t + 256 * m;
    int c = o >> 3, h = o & 7;
    float a = 0.f;
    for (int d = 0; d < 32; ++d) a += Wk[c * 256 + h * 32 + d] * qls[h * 32 + d];
    A_sc[o] = a * scale;
  }
  if (t < 8) {
    float a = 0.f;
    for (int d = 0; d < 32; ++d) a += bk[t * 32 + d] * qls[t * 32 + d];
    sb[t] = a * scale;
  }
}

// ---------------- Kp1: M[i][c] = cq_w[i,:] . ckT[:,c]  (ckT[j][c]=ck_w[c][j], col 320 = ck_b)
__global__ __launch_bounds__(352) void kp1(const float* __restrict__ cq_w,
    const float* __restrict__ cq_b, const float* __restrict__ ck_w,
    const float* __restrict__ ck_b, float* __restrict__ M, float* __restrict__ vbias) {
  __shared__ float row[256];
  int i = blockIdx.x, t = threadIdx.x;
  if (t < 256) row[t] = cq_w[i * 256 + t];
  __syncthreads();
  if (t < TDIM) {
    float a = 0.f;
    if (t < 320) { const float* w = ck_w + t * 256; for (int j = 0; j < 256; ++j) a += row[j] * w[j]; }
    else if (t == 320) { for (int j = 0; j < 256; ++j) a += row[j] * ck_b[j]; }
    M[i * TDIM + t] = a;
  }
  if (i == 0) {
    __syncthreads();
    if (t < 256) row[t] = cq_b[t];
    __syncthreads();
    if (t < TDIM) {
      float a = 0.f;
      if (t < 320) { const float* w = ck_w + t * 256; for (int j = 0; j < 256; ++j) a += row[j] * w[j]; }
      else if (t == 320) { for (int j = 0; j < 256; ++j) a += row[j] * ck_b[j]; }
      vbias[t] = a;
    }
  }
}

// ---------------- Kp2: MM[p][c] = Wo[p,:] . M[:,c] ; block 256: vb2[c] = bo.M[:,c] + vbias[c]
__global__ __launch_bounds__(352) void kp2(const float* __restrict__ Wo,
    const float* __restrict__ bo, const float* __restrict__ M,
    const float* __restrict__ vbias, float* __restrict__ MM, float* __restrict__ vb2) {
  __shared__ float row[256];
  int p = blockIdx.x, t = threadIdx.x;
  const float* src = (p < 256) ? (Wo + p * 256) : bo;
  if (t < 256) row[t] = src[t];
  __syncthreads();
  if (t < TDIM) {
    float a = 0.f;
    for (int i = 0; i < 256; ++i) a += row[i] * M[i * TDIM + t];
    if (p < 256) MM[p * TDIM + t] = a;
    else vb2[t] = a + vbias[t];
  }
}

// ---------------- Kp3: CV1[k][j] = cv_w[k,:] . cmlp_w1[:,j] ; block 320: cb1 = cv_b@w1m + b1m
__global__ __launch_bounds__(256) void kp3(const float* __restrict__ cv_w,
    const float* __restrict__ cv_b, const float* __restrict__ w1m,
    const float* __restrict__ b1m, float* __restrict__ CV1, float* __restrict__ cb1) {
  __shared__ float row[256];
  int k = blockIdx.x, t = threadIdx.x;
  const float* src = (k < 320) ? (cv_w + k * 256) : cv_b;
  row[t] = src[t];
  __syncthreads();
  float a = 0.f;
  for (int i = 0; i < 256; ++i) a += row[i] * w1m[i * 256 + t];
  if (k < 320) CV1[k * 256 + t] = a;
  else cb1[t] = a + b1m[t];
}

// ---------------- Kcast: W1t[n][k] = bf16(ffn_w1[k][n]) (512x256), W2t[n][k] = bf16(ffn_w2[k][n]) (256x512)
__global__ __launch_bounds__(256) void kcast(const float* __restrict__ fw1,
    const float* __restrict__ fw2, unsigned short* __restrict__ W1t,
    unsigned short* __restrict__ W2t) {
  int b = blockIdx.x, t = threadIdx.x;
  if (b < 512) {
    W1t[b * 256 + t] = f2bfu(fw1[t * 512 + b]);
  } else {
    int n = b - 512;
    for (int m = 0; m < 2; ++m) {
      int k = t + 256 * m;
      W2t[n * 512 + k] = f2bfu(fw2[k * 256 + n]);
    }
  }
}

// ---------------- KG1: PMA scores + softmax + per-head weighted sums y (4 blocks / wg)
__global__ __launch_bounds__(256) void kg1(const float* __restrict__ x,
    const float* __restrict__ A_sc, const float* __restrict__ sb,
    unsigned short* __restrict__ y_bf) {
  __shared__ unsigned short xs[64][264];
  __shared__ float Als[2048];
  __shared__ float sbl[8];
  __shared__ float s_l[64][8];
  __shared__ float w_l[64][8];
  int t = threadIdx.x, wg = blockIdx.x;
  long a0 = (long)wg * 64;
  const float4* x4 = (const float4*)(x + a0 * 256);
  for (int m = 0; m < 16; ++m) {
    int f4 = t + 256 * m;
    int row = f4 >> 6, c4 = f4 & 63;
    float4 v = x4[f4];
    ushort4 u;
    u.x = f2bfu(v.x); u.y = f2bfu(v.y); u.z = f2bfu(v.z); u.w = f2bfu(v.w);
    *(ushort4*)&xs[row][c4 * 4] = u;
  }
  for (int m = 0; m < 8; ++m) Als[t + 256 * m] = A_sc[t + 256 * m];
  if (t < 8) sbl[t] = sb[t];
  __syncthreads();
  for (int m = 0; m < 2; ++m) {
    int o = t + 256 * m;
    int i = o >> 3, h = o & 7;
    float a = sbl[h];
    for (int c8 = 0; c8 < 32; ++c8) {
      short8 v = *(const short8*)&xs[i][c8 * 8];
#pragma unroll
      for (int j = 0; j < 8; ++j)
        a += bfu2f((unsigned short)v[j]) * Als[(c8 * 8 + j) * 8 + h];
    }
    s_l[i][h] = a;
  }
  __syncthreads();
  if (t < 32) {
    int b = t >> 3, h = t & 7;
    float mx = -1e30f;
    for (int i = 0; i < 16; ++i) mx = fmaxf(mx, s_l[b * 16 + i][h]);
    float se = 0.f;
    for (int i = 0; i < 16; ++i) se += __expf(s_l[b * 16 + i][h] - mx);
    float inv = 1.f / fmaxf(se, 1e-20f);
    for (int i = 0; i < 16; ++i) w_l[b * 16 + i][h] = __expf(s_l[b * 16 + i][h] - mx) * inv;
  }
  __syncthreads();
  float yacc[32];
  for (int k = 0; k < 32; ++k) yacc[k] = 0.f;
  for (int b = 0; b < 4; ++b)
    for (int i = 0; i < 16; ++i) {
      float xv = bfu2f(xs[b * 16 + i][t]);
      for (int h = 0; h < 8; ++h) yacc[b * 8 + h] += w_l[b * 16 + i][h] * xv;
    }
  for (int b = 0; b < 4; ++b)
    for (int h = 0; h < 8; ++h)
      y_bf[((long)(wg * 4 + b) * 8 + h) * 256 + t] = f2bfu(yacc[b * 8 + h]);
}

// ---------------- G2: BP[b][j] = y[b][j>>5] . Wv[:,j] + bv[j]   (16 blocks / wg)
__global__ __launch_bounds__(256) void g2k(const unsigned short* __restrict__ y_bf,
    const float* __restrict__ Wv, const float* __restrict__ bv,
    unsigned short* __restrict__ BP_bf) {
  __shared__ unsigned short ys[8][8][264];
  int t = threadIdx.x;
  int B0 = blockIdx.x * 16;
  int h = t >> 5;
  float bvj = bv[t];
  for (int g = 0; g < 2; ++g) {
    __syncthreads();
    for (int m = 0; m < 8; ++m) {
      int flat = (t + 256 * m) * 8;
      int bb = flat >> 11, rem = flat & 2047;
      int hh = rem >> 8, c = rem & 255;
      short8 v = *(const short8*)(y_bf + ((long)(B0 + g * 8 + bb) * 8 + hh) * 256 + c);
      *(short8*)&ys[bb][hh][c] = v;
    }
    __syncthreads();
    float acc[8];
    for (int bb = 0; bb < 8; ++bb) acc[bb] = bvj;
    for (int c = 0; c < 256; ++c) {
      float w = Wv[c * 256 + t];
      for (int bb = 0; bb < 8; ++bb) acc[bb] += w * bfu2f(ys[bb][h][c]);
    }
    for (int bb = 0; bb < 8; ++bb)
      BP_bf[(long)(B0 + g * 8 + bb) * 256 + t] = f2bfu(acc[bb]);
  }
}

// ---------------- Gb1: T[b][c] = BP[b,:] . MM[:,c] + vb2[c]   (16 blocks / wg)
__global__ __launch_bounds__(256) void gb1(const unsigned short* __restrict__ BP_bf,
    const float* __restrict__ MM, const float* __restrict__ vb2, float* __restrict__ T) {
  __shared__ float rb[16][257];
  int t = threadIdx.x;
  int B0 = blockIdx.x * 16;
  for (int m = 0; m < 16; ++m) {
    int flat = t + 256 * m;
    int r = flat >> 8, c = flat & 255;
    rb[r][c] = bfu2f(BP_bf[(long)(B0 + r) * 256 + c]);
  }
  __syncthreads();
  for (int chunk = 0; chunk < 2; ++chunk) {
    int c = chunk * 256 + t;
    if (c < TDIM) {
      float vb = vb2[c];
      for (int g = 0; g < 2; ++g) {
        float acc[8];
        for (int bb = 0; bb < 8; ++bb) acc[bb] = vb;
        for (int j = 0; j < 256; ++j) {
          float w = MM[j * TDIM + c];
          for (int bb = 0; bb < 8; ++bb) acc[bb] += w * rb[g * 8 + bb][j];
        }
        for (int bb = 0; bb < 8; ++bb) T[(long)(B0 + g * 8 + bb) * TDIM + c] = acc[bb];
      }
    }
  }
}

// ---------------- KG3: geometry + cross-attn scores + softmax + z (4 blocks / wg)
__global__ __launch_bounds__(256) void kg3(const float* __restrict__ x,
    const float* __restrict__ pos, const float* __restrict__ T,
    const float* __restrict__ centers, const float* __restrict__ widths,
    const float* __restrict__ geom_w, const float* __restrict__ geom_b,
    unsigned short* __restrict__ z_bf) {
  __shared__ unsigned short xs[64][264];
  __shared__ float rbfp[64][65];
  __shared__ float rbfl[64][17];
  __shared__ float Tls[4][352];
  __shared__ float ps[64][3];
  __shared__ float cent[4][3];
  __shared__ float ctr[16], wid[16];
  __shared__ float scl[64], w2l[64];
  int t = threadIdx.x, wg = blockIdx.x;
  long a0 = (long)wg * 64;
  int b0 = wg * 4;
  const float4* x4 = (const float4*)(x + a0 * 256);
  for (int m = 0; m < 16; ++m) {
    int f4 = t + 256 * m;
    int row = f4 >> 6, c4 = f4 & 63;
    float4 v = x4[f4];
    ushort4 u;
    u.x = f2bfu(v.x); u.y = f2bfu(v.y); u.z = f2bfu(v.z); u.w = f2bfu(v.w);
    *(ushort4*)&xs[row][c4 * 4] = u;
  }
  if (t < 192) ps[t / 3][t % 3] = pos[a0 * 3 + t];
  if (t >= 224 && t < 240) ctr[t - 224] = centers[t - 224];
  if (t >= 240) wid[t - 240] = widths[t - 240];
  for (int b = 0; b < 4; ++b) {
    Tls[b][t] = T[(long)(b0 + b) * TDIM + t];
    if (t < 80) Tls[b][256 + t] = T[(long)(b0 + b) * TDIM + 256 + t];
  }
  __syncthreads();
  if (t < 12) {
    int b = t / 3, d = t % 3;
    float s = 0.f;
    for (int i = 0; i < 16; ++i) s += ps[b * 16 + i][d];
    cent[b][d] = s * 0.0625f;
  }
  __syncthreads();
  if (t < 64) {
    int b = t >> 4;
    float dx = ps[t][0] - cent[b][0];
    float dy = ps[t][1] - cent[b][1];
    float dz = ps[t][2] - cent[b][2];
    float dist = sqrtf(dx * dx + dy * dy + dz * dz);
    for (int r = 0; r < 16; ++r) {
      float dd = dist - ctr[r];
      rbfl[t][r] = __expf(-dd * dd / (2.f * wid[r] * wid[r]));
    }
  }
  __syncthreads();
  {
    int i = t >> 2, q0 = (t & 3) * 16;
    for (int q = q0; q < q0 + 16; ++q) {
      float a = geom_b[q];
      for (int r = 0; r < 16; ++r) a += rbfl[i][r] * geom_w[r * 64 + q];
      rbfp[i][q] = a;
    }
  }
  __syncthreads();
  {
    int i = t >> 2, p = t & 3, b = i >> 4;
    float a = 0.f;
    for (int c8 = 0; c8 < 8; ++c8) {
      short8 v = *(const short8*)&xs[i][p * 64 + c8 * 8];
#pragma unroll
      for (int j = 0; j < 8; ++j)
        a += bfu2f((unsigned short)v[j]) * Tls[b][p * 64 + c8 * 8 + j];
    }
    for (int q = p * 16; q < p * 16 + 16; ++q) a += rbfp[i][q] * Tls[b][256 + q];
    a += __shfl_xor(a, 1);
    a += __shfl_xor(a, 2);
    float sc = (a + Tls[b][320]) * 0.0625f;  // / sqrt(256)
    if (p == 0) scl[i] = sc;
  }
  __syncthreads();
  if (t < 4) {
    float mx = -1e30f;
    for (int i = 0; i < 16; ++i) mx = fmaxf(mx, scl[t * 16 + i]);
    float se = 0.f;
    for (int i = 0; i < 16; ++i) se += __expf(scl[t * 16 + i] - mx);
    float inv = 1.f / fmaxf(se, 1e-20f);
    for (int i = 0; i < 16; ++i) w2l[t * 16 + i] = __expf(scl[t * 16 + i] - mx) * inv;
  }
  __syncthreads();
  for (int b = 0; b < 4; ++b) {
    float zv = 0.f;
    for (int i = 0; i < 16; ++i) zv += w2l[b * 16 + i] * bfu2f(xs[b * 16 + i][t]);
    z_bf[(long)(b0 + b) * 320 + t] = f2bfu(zv);
  }
  {
    int q = t & 63, b = t >> 6;
    float zq = 0.f;
    for (int i = 0; i < 16; ++i) zq += w2l[b * 16 + i] * rbfp[b * 16 + i][q];
    z_bf[(long)(b0 + b) * 320 + 256 + q] = f2bfu(zq);
  }
}

// ---------------- Gb2: upd = relu(z@CV1+cb1)@cmlp_w2 + cmlp_b2   (16 blocks / wg)
__global__ __launch_bounds__(256) void gb2(const unsigned short* __restrict__ z_bf,
    const float* __restrict__ CV1, const float* __restrict__ cb1,
    const float* __restrict__ W2m, const float* __restrict__ b2m,
    float* __restrict__ upd) {
  __shared__ float zrb[16][321];
  __shared__ float prb[16][257];
  int t = threadIdx.x;
  int B0 = blockIdx.x * 16;
  for (int m = 0; m < 20; ++m) {
    int flat = t + 256 * m;
    int r = flat / 320, c = flat - r * 320;
    zrb[r][c] = bfu2f(z_bf[(long)(B0 + r) * 320 + c]);
  }
  __syncthreads();
  float cb = cb1[t];
  for (int g = 0; g < 2; ++g) {
    float acc[8];
    for (int bb = 0; bb < 8; ++bb) acc[bb] = cb;
    for (int k = 0; k < 320; ++k) {
      float w = CV1[k * 256 + t];
      for (int bb = 0; bb < 8; ++bb) acc[bb] += w * zrb[g * 8 + bb][k];
    }
    for (int bb = 0; bb < 8; ++bb) prb[g * 8 + bb][t] = fmaxf(acc[bb], 0.f);
  }
  __syncthreads();
  float b2 = b2m[t];
  for (int g = 0; g < 2; ++g) {
    float acc[8];
    for (int bb = 0; bb < 8; ++bb) acc[bb] = b2;
    for (int k = 0; k < 256; ++k) {
      float w = W2m[k * 256 + t];
      for (int bb = 0; bb < 8; ++bb) acc[bb] += w * prb[g * 8 + bb][k];
    }
    for (int bb = 0; bb < 8; ++bb) upd[(long)(B0 + g * 8 + bb) * 256 + t] = acc[bb];
  }
}

// ---------------- KF: LN1 + FFN (bf16 MFMA) + residual + LN2
// 64 atoms / wg, 8 waves (512 threads). All global loads/stores wave-contiguous.
__global__ __launch_bounds__(512, 4) void kf(const float* __restrict__ x,
    const float* __restrict__ upd, const unsigned short* __restrict__ W1t,
    const unsigned short* __restrict__ W2t, const float* __restrict__ b1,
    const float* __restrict__ b2, const float* __restrict__ g1,
    const float* __restrict__ be1, const float* __restrict__ g2,
    const float* __restrict__ be2, float* __restrict__ out) {
  __shared__ unsigned short x1s[64][280];  // post-LN1 activations (bf16)
  __shared__ unsigned short hs[64][136];   // 128-wide hidden slice (bf16)
  int t = threadIdx.x, wg = blockIdx.x;
  long a0 = (long)wg * 64;
  int b0 = wg * 4;
  int lane = t & 63, w = t >> 6;           // w in 0..7
  int lrow = lane & 15, hi = lane >> 4;    // hi in 0..3
  int lk = hi * 8;

  // ---- LN1: wave w handles rows w*8 .. w*8+7; loads 1KB contiguous per row
  {
    float4 gv1 = ((const float4*)g1)[lane];
    float4 bv1 = ((const float4*)be1)[lane];
#pragma unroll
    for (int rr = 0; rr < 8; ++rr) {
      int row = w * 8 + rr;
      float4 xv = ((const float4*)(x + (a0 + row) * 256))[lane];
      float4 uv = ((const float4*)(upd + (long)(b0 + (row >> 4)) * 256))[lane];
      float4 v;
      v.x = xv.x + uv.x; v.y = xv.y + uv.y; v.z = xv.z + uv.z; v.w = xv.w + uv.w;
      float s = v.x + v.y + v.z + v.w;
      float sq = v.x * v.x + v.y * v.y + v.z * v.z + v.w * v.w;
#pragma unroll
      for (int d = 1; d < 64; d <<= 1) { s += __shfl_xor(s, d); sq += __shfl_xor(sq, d); }
      float mu = s * (1.f / 256.f);
      float var = sq * (1.f / 256.f) - mu * mu;
      float rstd = rsqrtf(fmaxf(var, 0.f) + 1e-5f);
      ushort4 u;
      u.x = f2bfu((v.x - mu) * rstd * gv1.x + bv1.x);
      u.y = f2bfu((v.y - mu) * rstd * gv1.y + bv1.y);
      u.z = f2bfu((v.z - mu) * rstd * gv1.z + bv1.z);
      u.w = f2bfu((v.w - mu) * rstd * gv1.w + bv1.w);
      *(ushort4*)&x1s[row][lane * 4] = u;
    }
  }
  __syncthreads();

  floatx4 zero = {0.f, 0.f, 0.f, 0.f};
  floatx4 acc2[4][2];
  for (int rb = 0; rb < 4; ++rb)
    for (int cb = 0; cb < 2; ++cb) acc2[rb][cb] = zero;

  for (int s = 0; s < 4; ++s) {
    // GEMM1: this wave computes cols s*128 + w*16 + lrow (16 cols) for all 64 rows
    floatx4 acc1[4] = {zero, zero, zero, zero};
    int bcol = s * 128 + w * 16 + lrow;
    const short8* wp = (const short8*)(W1t + bcol * 256 + lk);
#pragma unroll
    for (int k0 = 0; k0 < 8; ++k0) {
      short8 bf = wp[k0 * 4];
      short8 af0 = *(const short8*)&x1s[0 + lrow][k0 * 32 + lk];
      short8 af1 = *(const short8*)&x1s[16 + lrow][k0 * 32 + lk];
      short8 af2 = *(const short8*)&x1s[32 + lrow][k0 * 32 + lk];
      short8 af3 = *(const short8*)&x1s[48 + lrow][k0 * 32 + lk];
      acc1[0] = __builtin_amdgcn_mfma_f32_16x16x32_bf16(af0, bf, acc1[0], 0, 0, 0);
      acc1[1] = __builtin_amdgcn_mfma_f32_16x16x32_bf16(af1, bf, acc1[1], 0, 0, 0);
      acc1[2] = __builtin_amdgcn_mfma_f32_16x16x32_bf16(af2, bf, acc1[2], 0, 0, 0);
      acc1[3] = __builtin_amdgcn_mfma_f32_16x16x32_bf16(af3, bf, acc1[3], 0, 0, 0);
    }
    float bias1 = b1[bcol];
    __syncthreads();  // previous GEMM2 finished reading hs
#pragma unroll
    for (int rb = 0; rb < 4; ++rb)
      for (int i = 0; i < 4; ++i) {
        float v = fmaxf(acc1[rb][i] + bias1, 0.f);
        hs[rb * 16 + hi * 4 + i][w * 16 + lrow] = f2bfu(v);
      }
    __syncthreads();
    // GEMM2 partial: K-slice s*128..s*128+127; this wave owns cols w*32 + cb*16
#pragma unroll
    for (int ks = 0; ks < 4; ++ks) {
      short8 a2[4];
      for (int rb = 0; rb < 4; ++rb)
        a2[rb] = *(const short8*)&hs[rb * 16 + lrow][ks * 32 + lk];
      for (int cb = 0; cb < 2; ++cb) {
        int col = w * 32 + cb * 16 + lrow;
        short8 b2f = *(const short8*)(W2t + col * 512 + s * 128 + ks * 32 + lk);
        for (int rb = 0; rb < 4; ++rb)
          acc2[rb][cb] = __builtin_amdgcn_mfma_f32_16x16x32_bf16(a2[rb], b2f, acc2[rb][cb], 0, 0, 0);
      }
    }
  }

  // epilogue: residual (bf16 x1) + bias2, in-place into x1s
  for (int cb = 0; cb < 2; ++cb) {
    int col = w * 32 + cb * 16 + lrow;
    float b2v = b2[col];
    for (int rb = 0; rb < 4; ++rb)
      for (int i = 0; i < 4; ++i) {
        int row = rb * 16 + hi * 4 + i;
        float res = acc2[rb][cb][i] + b2v + bfu2f(x1s[row][col]);
        x1s[row][col] = f2bfu(res);
      }
  }
  __syncthreads();

  // ---- LN2 + coalesced store: wave w handles rows w*8 .. w*8+7
  {
    float4 gv2 = ((const float4*)g2)[lane];
    float4 bv2 = ((const float4*)be2)[lane];
#pragma unroll
    for (int rr = 0; rr < 8; ++rr) {
      int row = w * 8 + rr;
      ushort4 u = *(const ushort4*)&x1s[row][lane * 4];
      float v0 = bfu2f(u.x), v1 = bfu2f(u.y), v2 = bfu2f(u.z), v3 = bfu2f(u.w);
      float s = v0 + v1 + v2 + v3;
      float sq = v0 * v0 + v1 * v1 + v2 * v2 + v3 * v3;
#pragma unroll
      for (int d = 1; d < 64; d <<= 1) { s += __shfl_xor(s, d); sq += __shfl_xor(sq, d); }
      float mu = s * (1.f / 256.f);
      float var = sq * (1.f / 256.f) - mu * mu;
      float rstd = rsqrtf(fmaxf(var, 0.f) + 1e-5f);
      float4 o;
      o.x = (v0 - mu) * rstd * gv2.x + bv2.x;
      o.y = (v1 - mu) * rstd * gv2.y + bv2.y;
      o.z = (v2 - mu) * rstd * gv2.z + bv2.z;
      o.w = (v3 - mu) * rstd * gv2.w + bv2.w;
      ((float4*)(out + (a0 + row) * 256))[lane] = o;
    }
  }
}

extern "C" void kernel_launch(void* const* d_in, const int* in_sizes, int n_in,
                              void* d_out, int out_size, void* d_ws, size_t ws_size,
                              hipStream_t stream) {
  (void)in_sizes; (void)n_in; (void)out_size; (void)ws_size;
  const float* x    = (const float*)d_in[0];
  const float* pos  = (const float*)d_in[1];
  const float* seed = (const float*)d_in[4];
  const float* Wq   = (const float*)d_in[5];
  const float* bq   = (const float*)d_in[6];
  const float* Wk   = (const float*)d_in[7];
  const float* bk   = (const float*)d_in[8];
  const float* Wv   = (const float*)d_in[9];
  const float* bv   = (const float*)d_in[10];
  const float* Wo   = (const float*)d_in[11];
  const float* bo   = (const float*)d_in[12];
  const float* centers = (const float*)d_in[13];
  const float* widths  = (const float*)d_in[14];
  const float* geom_w  = (const float*)d_in[15];
  const float* geom_b  = (const float*)d_in[16];
  const float* cq_w = (const float*)d_in[17];
  const float* cq_b = (const float*)d_in[18];
  const float* ck_w = (const float*)d_in[19];
  const float* ck_b = (const float*)d_in[20];
  const float* cv_w = (const float*)d_in[21];
  const float* cv_b = (const float*)d_in[22];
  const float* w1m  = (const float*)d_in[23];
  const float* b1m  = (const float*)d_in[24];
  const float* w2m  = (const float*)d_in[25];
  const float* b2m  = (const float*)d_in[26];
  const float* fw1  = (const float*)d_in[27];
  const float* fb1  = (const float*)d_in[28];
  const float* fw2  = (const float*)d_in[29];
  const float* fb2  = (const float*)d_in[30];
  const float* g1   = (const float*)d_in[31];
  const float* be1  = (const float*)d_in[32];
  const float* g2   = (const float*)d_in[33];
  const float* be2  = (const float*)d_in[34];

  float* ws = (float*)d_ws;
  float* A_sc  = ws + 0;        // 2048
  float* sb    = ws + 2048;     // 64
  float* M     = ws + 2112;     // 256*336
  float* vbias = ws + 88128;    // 352
  float* MM    = ws + 88480;    // 256*336
  float* vb2   = ws + 174496;   // 352
  float* CV1   = ws + 174848;   // 320*256
  float* cb1   = ws + 256768;   // 256
  unsigned short* W1t = (unsigned short*)(ws + 257024);   // 512*256 bf16
  unsigned short* W2t = (unsigned short*)(ws + 322560);   // 256*512 bf16
  unsigned short* BP  = (unsigned short*)(ws + 388096);   // 8192*256 bf16
  unsigned short* zbf = (unsigned short*)(ws + 1436672);  // 8192*320 bf16
  float* updw = ws + 2747392;                             // 8192*256 f32
  // total ws use: ~19.4 MB

  float* outp = (float*)d_out;
  unsigned short* ybf = (unsigned short*)d_out;  // scratch in d_out: 8192*8*256 bf16 (33.5MB)
  float* T = outp + 16777216;                    // scratch in d_out: 8192*336 f32 (11MB)

  k0_prep<<<dim3(1), dim3(256), 0, stream>>>(seed, Wq, bq, Wk, bk, A_sc, sb);
  kp1<<<dim3(256), dim3(352), 0, stream>>>(cq_w, cq_b, ck_w, ck_b, M, vbias);
  kp2<<<dim3(257), dim3(352), 0, stream>>>(Wo, bo, M, vbias, MM, vb2);
  kp3<<<dim3(321), dim3(256), 0, stream>>>(cv_w, cv_b, w1m, b1m, CV1, cb1);
  kcast<<<dim3(768), dim3(256), 0, stream>>>(fw1, fw2, W1t, W2t);
  kg1<<<dim3(2048), dim3(256), 0, stream>>>(x, A_sc, sb, ybf);
  g2k<<<dim3(512), dim3(256), 0, stream>>>(ybf, Wv, bv, BP);
  gb1<<<dim3(512), dim3(256), 0, stream>>>(BP, MM, vb2, T);
  kg3<<<dim3(2048), dim3(256), 0, stream>>>(x, pos, T, centers, widths, geom_w, geom_b, zbf);
  gb2<<<dim3(512), dim3(256), 0, stream>>>(zbf, CV1, cb1, w2m, b2m, updw);
  kf<<<dim3(2048), dim3(512), 0, stream>>>(x, updw, W1t, W2t, fb1, fb2, g1, be1, g2, be2, outp);
}

// Round 3
// 565.667 us; speedup vs baseline: 1.4609x; 1.3297x over previous
//
#include <hip/hip_runtime.h>
#include <hip/hip_bf16.h>

// Sizes (fixed by the problem)
#define NATOMS 131072
#define NBLK   8192
#define HDIM   256
#define NHEAD  8
#define TDIM   336   // 320 aug dims + 1 (ck_b . Q) + pad

typedef __attribute__((ext_vector_type(8))) short short8;
typedef __attribute__((ext_vector_type(4))) float floatx4;

__device__ __forceinline__ float bfu2f(unsigned short u) {
  unsigned int v = ((unsigned int)u) << 16;
  return __builtin_bit_cast(float, v);
}
__device__ __forceinline__ unsigned short f2bfu(float f) {
  unsigned int u = __builtin_bit_cast(unsigned int, f);
  u += 0x7fffu + ((u >> 16) & 1u);
  return (unsigned short)(u >> 16);
}

// ---------------- K0: q = seed@Wq+bq ; A_sc[c][h] = scale * Wk[c, h*32+d] . q[h*32+d] ; sb[h]
__global__ __launch_bounds__(256) void k0_prep(const float* __restrict__ seed,
    const float* __restrict__ Wq, const float* __restrict__ bq,
    const float* __restrict__ Wk, const float* __restrict__ bk,
    float* __restrict__ A_sc, float* __restrict__ sb) {
  __shared__ float qls[256];
  int t = threadIdx.x;
  float acc = bq[t];
  for (int c = 0; c < 256; ++c) acc += seed[c] * Wq[c * 256 + t];
  qls[t] = acc;
  __syncthreads();
  const float scale = 0.17677669529663687f;  // 1/sqrt(32)
  for (int m = 0; m < 8; ++m) {
    int o = t + 256 * m;
    int c = o >> 3, h = o & 7;
    float a = 0.f;
    for (int d = 0; d < 32; ++d) a += Wk[c * 256 + h * 32 + d] * qls[h * 32 + d];
    A_sc[o] = a * scale;
  }
  if (t < 8) {
    float a = 0.f;
    for (int d = 0; d < 32; ++d) a += bk[t * 32 + d] * qls[t * 32 + d];
    sb[t] = a * scale;
  }
}

// ---------------- Kp1: M[i][c] = cq_w[i,:] . ckT[:,c]  (ckT[j][c]=ck_w[c][j], col 320 = ck_b)
__global__ __launch_bounds__(352) void kp1(const float* __restrict__ cq_w,
    const float* __restrict__ cq_b, const float* __restrict__ ck_w,
    const float* __restrict__ ck_b, float* __restrict__ M, float* __restrict__ vbias) {
  __shared__ float row[256];
  int i = blockIdx.x, t = threadIdx.x;
  if (t < 256) row[t] = cq_w[i * 256 + t];
  __syncthreads();
  if (t < TDIM) {
    float a = 0.f;
    if (t < 320) { const float* w = ck_w + t * 256; for (int j = 0; j < 256; ++j) a += row[j] * w[j]; }
    else if (t == 320) { for (int j = 0; j < 256; ++j) a += row[j] * ck_b[j]; }
    M[i * TDIM + t] = a;
  }
  if (i == 0) {
    __syncthreads();
    if (t < 256) row[t] = cq_b[t];
    __syncthreads();
    if (t < TDIM) {
      float a = 0.f;
      if (t < 320) { const float* w = ck_w + t * 256; for (int j = 0; j < 256; ++j) a += row[j] * w[j]; }
      else if (t == 320) { for (int j = 0; j < 256; ++j) a += row[j] * ck_b[j]; }
      vbias[t] = a;
    }
  }
}

// ---------------- Kp2: MM[p][c] = Wo[p,:] . M[:,c] ; block 256: vb2[c] = bo.M[:,c] + vbias[c]
__global__ __launch_bounds__(352) void kp2(const float* __restrict__ Wo,
    const float* __restrict__ bo, const float* __restrict__ M,
    const float* __restrict__ vbias, float* __restrict__ MM, float* __restrict__ vb2) {
  __shared__ float row[256];
  int p = blockIdx.x, t = threadIdx.x;
  const float* src = (p < 256) ? (Wo + p * 256) : bo;
  if (t < 256) row[t] = src[t];
  __syncthreads();
  if (t < TDIM) {
    float a = 0.f;
    for (int i = 0; i < 256; ++i) a += row[i] * M[i * TDIM + t];
    if (p < 256) MM[p * TDIM + t] = a;
    else vb2[t] = a + vbias[t];
  }
}

// ---------------- Kp3: CV1[k][j] = cv_w[k,:] . cmlp_w1[:,j] ; block 320: cb1 = cv_b@w1m + b1m
__global__ __launch_bounds__(256) void kp3(const float* __restrict__ cv_w,
    const float* __restrict__ cv_b, const float* __restrict__ w1m,
    const float* __restrict__ b1m, float* __restrict__ CV1, float* __restrict__ cb1) {
  __shared__ float row[256];
  int k = blockIdx.x, t = threadIdx.x;
  const float* src = (k < 320) ? (cv_w + k * 256) : cv_b;
  row[t] = src[t];
  __syncthreads();
  float a = 0.f;
  for (int i = 0; i < 256; ++i) a += row[i] * w1m[i * 256 + t];
  if (k < 320) CV1[k * 256 + t] = a;
  else cb1[t] = a + b1m[t];
}

// ---------------- Kcast: W1t[n][k] = bf16(ffn_w1[k][n]) (512x256), W2t[n][k] = bf16(ffn_w2[k][n]) (256x512)
__global__ __launch_bounds__(256) void kcast(const float* __restrict__ fw1,
    const float* __restrict__ fw2, unsigned short* __restrict__ W1t,
    unsigned short* __restrict__ W2t) {
  int b = blockIdx.x, t = threadIdx.x;
  if (b < 512) {
    W1t[b * 256 + t] = f2bfu(fw1[t * 512 + b]);
  } else {
    int n = b - 512;
    for (int m = 0; m < 2; ++m) {
      int k = t + 256 * m;
      W2t[n * 512 + k] = f2bfu(fw2[k * 256 + n]);
    }
  }
}

// ---------------- KG1: PMA scores + softmax + per-head weighted sums y (4 blocks / wg) -> y f32
__global__ __launch_bounds__(256) void kg1(const float* __restrict__ x,
    const float* __restrict__ A_sc, const float* __restrict__ sb,
    float* __restrict__ y_f) {
  __shared__ unsigned short xs[64][264];
  __shared__ float Als[2048];
  __shared__ float sbl[8];
  __shared__ float s_l[64][8];
  __shared__ float w_l[64][8];
  int t = threadIdx.x, wg = blockIdx.x;
  long a0 = (long)wg * 64;
  const float4* x4 = (const float4*)(x + a0 * 256);
  for (int m = 0; m < 16; ++m) {
    int f4 = t + 256 * m;
    int row = f4 >> 6, c4 = f4 & 63;
    float4 v = x4[f4];
    ushort4 u;
    u.x = f2bfu(v.x); u.y = f2bfu(v.y); u.z = f2bfu(v.z); u.w = f2bfu(v.w);
    *(ushort4*)&xs[row][c4 * 4] = u;
  }
  for (int m = 0; m < 8; ++m) Als[t + 256 * m] = A_sc[t + 256 * m];
  if (t < 8) sbl[t] = sb[t];
  __syncthreads();
  for (int m = 0; m < 2; ++m) {
    int o = t + 256 * m;
    int i = o >> 3, h = o & 7;
    float a = sbl[h];
    for (int c8 = 0; c8 < 32; ++c8) {
      short8 v = *(const short8*)&xs[i][c8 * 8];
#pragma unroll
      for (int j = 0; j < 8; ++j)
        a += bfu2f((unsigned short)v[j]) * Als[(c8 * 8 + j) * 8 + h];
    }
    s_l[i][h] = a;
  }
  __syncthreads();
  if (t < 32) {
    int b = t >> 3, h = t & 7;
    float mx = -1e30f;
    for (int i = 0; i < 16; ++i) mx = fmaxf(mx, s_l[b * 16 + i][h]);
    float se = 0.f;
    for (int i = 0; i < 16; ++i) se += __expf(s_l[b * 16 + i][h] - mx);
    float inv = 1.f / fmaxf(se, 1e-20f);
    for (int i = 0; i < 16; ++i) w_l[b * 16 + i][h] = __expf(s_l[b * 16 + i][h] - mx) * inv;
  }
  __syncthreads();
  float yacc[32];
  for (int k = 0; k < 32; ++k) yacc[k] = 0.f;
  for (int b = 0; b < 4; ++b)
    for (int i = 0; i < 16; ++i) {
      float xv = bfu2f(xs[b * 16 + i][t]);
      for (int h = 0; h < 8; ++h) yacc[b * 8 + h] += w_l[b * 16 + i][h] * xv;
    }
  for (int b = 0; b < 4; ++b)
    for (int h = 0; h < 8; ++h)
      y_f[((long)(wg * 4 + b) * 8 + h) * 256 + t] = yacc[b * 8 + h];
}

// ---------------- G2: BP[b][j] = y[b][j>>5] . Wv[:,j] + bv[j]   (4 blocks / wg, f32 y in LDS)
__global__ __launch_bounds__(256, 4) void g2k(const float* __restrict__ y_f,
    const float* __restrict__ Wv, const float* __restrict__ bv,
    float* __restrict__ BPf) {
  __shared__ float ys[4][8][260];
  int t = threadIdx.x;
  int B0 = blockIdx.x * 4;
  int h = t >> 5;
#pragma unroll
  for (int m = 0; m < 32; ++m) {
    int flat = t + 256 * m;
    int bb = flat >> 11, rem = flat & 2047;
    ys[bb][rem >> 8][rem & 255] = y_f[((long)(B0 + bb) * 8 + (rem >> 8)) * 256 + (rem & 255)];
  }
  __syncthreads();
  float acc[4];
  float bvj = bv[t];
#pragma unroll
  for (int bb = 0; bb < 4; ++bb) acc[bb] = bvj;
  const float* wp = Wv + t;
  for (int c = 0; c < 256; c += 4) {
    float w0 = wp[(c + 0) * 256];
    float w1 = wp[(c + 1) * 256];
    float w2 = wp[(c + 2) * 256];
    float w3 = wp[(c + 3) * 256];
#pragma unroll
    for (int bb = 0; bb < 4; ++bb) {
      float4 y4 = *(const float4*)&ys[bb][h][c];
      acc[bb] += w0 * y4.x + w1 * y4.y + w2 * y4.z + w3 * y4.w;
    }
  }
#pragma unroll
  for (int bb = 0; bb < 4; ++bb)
    BPf[(long)(B0 + bb) * 256 + t] = acc[bb];
}

// ---------------- Gb1: T[b][c] = BP[b,:] . MM[:,c] + vb2[c]   (8 blocks / wg, 384 thr)
__global__ __launch_bounds__(384, 6) void gb1(const float* __restrict__ BPf,
    const float* __restrict__ MM, const float* __restrict__ vb2, float* __restrict__ T) {
  __shared__ float rb[8][260];
  int t = threadIdx.x;
  int B0 = blockIdx.x * 8;
  for (int idx = t; idx < 2048; idx += 384) {
    int r = idx >> 8, c = idx & 255;
    rb[r][c] = BPf[(long)(B0 + r) * 256 + c];
  }
  __syncthreads();
  if (t < TDIM) {
    int c = t;
    float vb = vb2[c];
    float acc[8];
#pragma unroll
    for (int bb = 0; bb < 8; ++bb) acc[bb] = vb;
    const float* mc = MM + c;
    for (int j = 0; j < 256; j += 4) {
      float w0 = mc[(j + 0) * TDIM];
      float w1 = mc[(j + 1) * TDIM];
      float w2 = mc[(j + 2) * TDIM];
      float w3 = mc[(j + 3) * TDIM];
#pragma unroll
      for (int bb = 0; bb < 8; ++bb) {
        float4 r4 = *(const float4*)&rb[bb][j];
        acc[bb] += w0 * r4.x + w1 * r4.y + w2 * r4.z + w3 * r4.w;
      }
    }
#pragma unroll
    for (int bb = 0; bb < 8; ++bb)
      T[(long)(B0 + bb) * TDIM + c] = acc[bb];
  }
}

// ---------------- KG3: geometry + cross-attn scores + softmax + z (4 blocks / wg) -> z f32
__global__ __launch_bounds__(256) void kg3(const float* __restrict__ x,
    const float* __restrict__ pos, const float* __restrict__ T,
    const float* __restrict__ centers, const float* __restrict__ widths,
    const float* __restrict__ geom_w, const float* __restrict__ geom_b,
    float* __restrict__ z_f) {
  __shared__ unsigned short xs[64][264];
  __shared__ float rbfp[64][65];
  __shared__ float rbfl[64][17];
  __shared__ float Tls[4][352];
  __shared__ float ps[64][3];
  __shared__ float cent[4][3];
  __shared__ float ctr[16], wid[16];
  __shared__ float scl[64], w2l[64];
  int t = threadIdx.x, wg = blockIdx.x;
  long a0 = (long)wg * 64;
  int b0 = wg * 4;
  const float4* x4 = (const float4*)(x + a0 * 256);
  for (int m = 0; m < 16; ++m) {
    int f4 = t + 256 * m;
    int row = f4 >> 6, c4 = f4 & 63;
    float4 v = x4[f4];
    ushort4 u;
    u.x = f2bfu(v.x); u.y = f2bfu(v.y); u.z = f2bfu(v.z); u.w = f2bfu(v.w);
    *(ushort4*)&xs[row][c4 * 4] = u;
  }
  if (t < 192) ps[t / 3][t % 3] = pos[a0 * 3 + t];
  if (t >= 224 && t < 240) ctr[t - 224] = centers[t - 224];
  if (t >= 240) wid[t - 240] = widths[t - 240];
  for (int b = 0; b < 4; ++b) {
    Tls[b][t] = T[(long)(b0 + b) * TDIM + t];
    if (t < 80) Tls[b][256 + t] = T[(long)(b0 + b) * TDIM + 256 + t];
  }
  __syncthreads();
  if (t < 12) {
    int b = t / 3, d = t % 3;
    float s = 0.f;
    for (int i = 0; i < 16; ++i) s += ps[b * 16 + i][d];
    cent[b][d] = s * 0.0625f;
  }
  __syncthreads();
  if (t < 64) {
    int b = t >> 4;
    float dx = ps[t][0] - cent[b][0];
    float dy = ps[t][1] - cent[b][1];
    float dz = ps[t][2] - cent[b][2];
    float dist = sqrtf(dx * dx + dy * dy + dz * dz);
    for (int r = 0; r < 16; ++r) {
      float dd = dist - ctr[r];
      rbfl[t][r] = __expf(-dd * dd / (2.f * wid[r] * wid[r]));
    }
  }
  __syncthreads();
  {
    int i = t >> 2, q0 = (t & 3) * 16;
    for (int q = q0; q < q0 + 16; ++q) {
      float a = geom_b[q];
      for (int r = 0; r < 16; ++r) a += rbfl[i][r] * geom_w[r * 64 + q];
      rbfp[i][q] = a;
    }
  }
  __syncthreads();
  {
    int i = t >> 2, p = t & 3, b = i >> 4;
    float a = 0.f;
    for (int c8 = 0; c8 < 8; ++c8) {
      short8 v = *(const short8*)&xs[i][p * 64 + c8 * 8];
#pragma unroll
      for (int j = 0; j < 8; ++j)
        a += bfu2f((unsigned short)v[j]) * Tls[b][p * 64 + c8 * 8 + j];
    }
    for (int q = p * 16; q < p * 16 + 16; ++q) a += rbfp[i][q] * Tls[b][256 + q];
    a += __shfl_xor(a, 1);
    a += __shfl_xor(a, 2);
    float sc = (a + Tls[b][320]) * 0.0625f;  // / sqrt(256)
    if (p == 0) scl[i] = sc;
  }
  __syncthreads();
  if (t < 4) {
    float mx = -1e30f;
    for (int i = 0; i < 16; ++i) mx = fmaxf(mx, scl[t * 16 + i]);
    float se = 0.f;
    for (int i = 0; i < 16; ++i) se += __expf(scl[t * 16 + i] - mx);
    float inv = 1.f / fmaxf(se, 1e-20f);
    for (int i = 0; i < 16; ++i) w2l[t * 16 + i] = __expf(scl[t * 16 + i] - mx) * inv;
  }
  __syncthreads();
  for (int b = 0; b < 4; ++b) {
    float zv = 0.f;
    for (int i = 0; i < 16; ++i) zv += w2l[b * 16 + i] * bfu2f(xs[b * 16 + i][t]);
    z_f[(long)(b0 + b) * 320 + t] = zv;
  }
  {
    int q = t & 63, b = t >> 6;
    float zq = 0.f;
    for (int i = 0; i < 16; ++i) zq += w2l[b * 16 + i] * rbfp[b * 16 + i][q];
    z_f[(long)(b0 + b) * 320 + 256 + q] = zq;
  }
}

// ---------------- Gb2: upd = relu(z@CV1+cb1)@cmlp_w2 + cmlp_b2   (8 blocks / wg)
__global__ __launch_bounds__(256, 4) void gb2(const float* __restrict__ z_f,
    const float* __restrict__ CV1, const float* __restrict__ cb1,
    const float* __restrict__ W2m, const float* __restrict__ b2m,
    float* __restrict__ upd) {
  __shared__ float zrb[8][324];
  __shared__ float prb[8][260];
  int t = threadIdx.x;
  int B0 = blockIdx.x * 8;
  for (int idx = t; idx < 8 * 320; idx += 256) {
    int r = idx / 320, c = idx - r * 320;
    zrb[r][c] = z_f[(long)(B0 + r) * 320 + c];
  }
  __syncthreads();
  {
    float cb = cb1[t];
    float acc[8];
#pragma unroll
    for (int bb = 0; bb < 8; ++bb) acc[bb] = cb;
    const float* wp = CV1 + t;
    for (int k = 0; k < 320; k += 4) {
      float w0 = wp[(k + 0) * 256];
      float w1 = wp[(k + 1) * 256];
      float w2 = wp[(k + 2) * 256];
      float w3 = wp[(k + 3) * 256];
#pragma unroll
      for (int bb = 0; bb < 8; ++bb) {
        float4 z4 = *(const float4*)&zrb[bb][k];
        acc[bb] += w0 * z4.x + w1 * z4.y + w2 * z4.z + w3 * z4.w;
      }
    }
#pragma unroll
    for (int bb = 0; bb < 8; ++bb) prb[bb][t] = fmaxf(acc[bb], 0.f);
  }
  __syncthreads();
  {
    float b2 = b2m[t];
    float acc[8];
#pragma unroll
    for (int bb = 0; bb < 8; ++bb) acc[bb] = b2;
    const float* wp = W2m + t;
    for (int k = 0; k < 256; k += 4) {
      float w0 = wp[(k + 0) * 256];
      float w1 = wp[(k + 1) * 256];
      float w2 = wp[(k + 2) * 256];
      float w3 = wp[(k + 3) * 256];
#pragma unroll
      for (int bb = 0; bb < 8; ++bb) {
        float4 p4 = *(const float4*)&prb[bb][k];
        acc[bb] += w0 * p4.x + w1 * p4.y + w2 * p4.z + w3 * p4.w;
      }
    }
#pragma unroll
    for (int bb = 0; bb < 8; ++bb)
      upd[(long)(B0 + bb) * 256 + t] = acc[bb];
  }
}

// ---------------- KF: LN1 + FFN (bf16 MFMA) + residual + LN2
// 64 atoms / wg, 8 waves (512 threads). All global loads/stores wave-contiguous.
__global__ __launch_bounds__(512, 4) void kf(const float* __restrict__ x,
    const float* __restrict__ upd, const unsigned short* __restrict__ W1t,
    const unsigned short* __restrict__ W2t, const float* __restrict__ b1,
    const float* __restrict__ b2, const float* __restrict__ g1,
    const float* __restrict__ be1, const float* __restrict__ g2,
    const float* __restrict__ be2, float* __restrict__ out) {
  __shared__ unsigned short x1s[64][280];  // post-LN1 activations (bf16)
  __shared__ unsigned short hs[64][136];   // 128-wide hidden slice (bf16)
  int t = threadIdx.x, wg = blockIdx.x;
  long a0 = (long)wg * 64;
  int b0 = wg * 4;
  int lane = t & 63, w = t >> 6;           // w in 0..7
  int lrow = lane & 15, hi = lane >> 4;    // hi in 0..3
  int lk = hi * 8;

  // ---- LN1: wave w handles rows w*8 .. w*8+7; loads 1KB contiguous per row
  {
    float4 gv1 = ((const float4*)g1)[lane];
    float4 bv1 = ((const float4*)be1)[lane];
#pragma unroll
    for (int rr = 0; rr < 8; ++rr) {
      int row = w * 8 + rr;
      float4 xv = ((const float4*)(x + (a0 + row) * 256))[lane];
      float4 uv = ((const float4*)(upd + (long)(b0 + (row >> 4)) * 256))[lane];
      float4 v;
      v.x = xv.x + uv.x; v.y = xv.y + uv.y; v.z = xv.z + uv.z; v.w = xv.w + uv.w;
      float s = v.x + v.y + v.z + v.w;
      float sq = v.x * v.x + v.y * v.y + v.z * v.z + v.w * v.w;
#pragma unroll
      for (int d = 1; d < 64; d <<= 1) { s += __shfl_xor(s, d); sq += __shfl_xor(sq, d); }
      float mu = s * (1.f / 256.f);
      float var = sq * (1.f / 256.f) - mu * mu;
      float rstd = rsqrtf(fmaxf(var, 0.f) + 1e-5f);
      ushort4 u;
      u.x = f2bfu((v.x - mu) * rstd * gv1.x + bv1.x);
      u.y = f2bfu((v.y - mu) * rstd * gv1.y + bv1.y);
      u.z = f2bfu((v.z - mu) * rstd * gv1.z + bv1.z);
      u.w = f2bfu((v.w - mu) * rstd * gv1.w + bv1.w);
      *(ushort4*)&x1s[row][lane * 4] = u;
    }
  }
  __syncthreads();

  floatx4 zero = {0.f, 0.f, 0.f, 0.f};
  floatx4 acc2[4][2];
  for (int rb = 0; rb < 4; ++rb)
    for (int cb = 0; cb < 2; ++cb) acc2[rb][cb] = zero;

  for (int s = 0; s < 4; ++s) {
    // GEMM1: this wave computes cols s*128 + w*16 + lrow (16 cols) for all 64 rows
    floatx4 acc1[4] = {zero, zero, zero, zero};
    int bcol = s * 128 + w * 16 + lrow;
    const short8* wp = (const short8*)(W1t + bcol * 256 + lk);
#pragma unroll
    for (int k0 = 0; k0 < 8; ++k0) {
      short8 bf = wp[k0 * 4];
      short8 af0 = *(const short8*)&x1s[0 + lrow][k0 * 32 + lk];
      short8 af1 = *(const short8*)&x1s[16 + lrow][k0 * 32 + lk];
      short8 af2 = *(const short8*)&x1s[32 + lrow][k0 * 32 + lk];
      short8 af3 = *(const short8*)&x1s[48 + lrow][k0 * 32 + lk];
      acc1[0] = __builtin_amdgcn_mfma_f32_16x16x32_bf16(af0, bf, acc1[0], 0, 0, 0);
      acc1[1] = __builtin_amdgcn_mfma_f32_16x16x32_bf16(af1, bf, acc1[1], 0, 0, 0);
      acc1[2] = __builtin_amdgcn_mfma_f32_16x16x32_bf16(af2, bf, acc1[2], 0, 0, 0);
      acc1[3] = __builtin_amdgcn_mfma_f32_16x16x32_bf16(af3, bf, acc1[3], 0, 0, 0);
    }
    float bias1 = b1[bcol];
    __syncthreads();  // previous GEMM2 finished reading hs
#pragma unroll
    for (int rb = 0; rb < 4; ++rb)
      for (int i = 0; i < 4; ++i) {
        float v = fmaxf(acc1[rb][i] + bias1, 0.f);
        hs[rb * 16 + hi * 4 + i][w * 16 + lrow] = f2bfu(v);
      }
    __syncthreads();
    // GEMM2 partial: K-slice s*128..s*128+127; this wave owns cols w*32 + cb*16
#pragma unroll
    for (int ks = 0; ks < 4; ++ks) {
      short8 a2[4];
      for (int rb = 0; rb < 4; ++rb)
        a2[rb] = *(const short8*)&hs[rb * 16 + lrow][ks * 32 + lk];
      for (int cb = 0; cb < 2; ++cb) {
        int col = w * 32 + cb * 16 + lrow;
        short8 b2f = *(const short8*)(W2t + col * 512 + s * 128 + ks * 32 + lk);
        for (int rb = 0; rb < 4; ++rb)
          acc2[rb][cb] = __builtin_amdgcn_mfma_f32_16x16x32_bf16(a2[rb], b2f, acc2[rb][cb], 0, 0, 0);
      }
    }
  }

  // epilogue: residual (bf16 x1) + bias2, in-place into x1s
  for (int cb = 0; cb < 2; ++cb) {
    int col = w * 32 + cb * 16 + lrow;
    float b2v = b2[col];
    for (int rb = 0; rb < 4; ++rb)
      for (int i = 0; i < 4; ++i) {
        int row = rb * 16 + hi * 4 + i;
        float res = acc2[rb][cb][i] + b2v + bfu2f(x1s[row][col]);
        x1s[row][col] = f2bfu(res);
      }
  }
  __syncthreads();

  // ---- LN2 + coalesced store: wave w handles rows w*8 .. w*8+7
  {
    float4 gv2 = ((const float4*)g2)[lane];
    float4 bv2 = ((const float4*)be2)[lane];
#pragma unroll
    for (int rr = 0; rr < 8; ++rr) {
      int row = w * 8 + rr;
      ushort4 u = *(const ushort4*)&x1s[row][lane * 4];
      float v0 = bfu2f(u.x), v1 = bfu2f(u.y), v2 = bfu2f(u.z), v3 = bfu2f(u.w);
      float s = v0 + v1 + v2 + v3;
      float sq = v0 * v0 + v1 * v1 + v2 * v2 + v3 * v3;
#pragma unroll
      for (int d = 1; d < 64; d <<= 1) { s += __shfl_xor(s, d); sq += __shfl_xor(sq, d); }
      float mu = s * (1.f / 256.f);
      float var = sq * (1.f / 256.f) - mu * mu;
      float rstd = rsqrtf(fmaxf(var, 0.f) + 1e-5f);
      float4 o;
      o.x = (v0 - mu) * rstd * gv2.x + bv2.x;
      o.y = (v1 - mu) * rstd * gv2.y + bv2.y;
      o.z = (v2 - mu) * rstd * gv2.z + bv2.z;
      o.w = (v3 - mu) * rstd * gv2.w + bv2.w;
      ((float4*)(out + (a0 + row) * 256))[lane] = o;
    }
  }
}

extern "C" void kernel_launch(void* const* d_in, const int* in_sizes, int n_in,
                              void* d_out, int out_size, void* d_ws, size_t ws_size,
                              hipStream_t stream) {
  (void)in_sizes; (void)n_in; (void)out_size; (void)ws_size;
  const float* x    = (const float*)d_in[0];
  const float* pos  = (const float*)d_in[1];
  const float* seed = (const float*)d_in[4];
  const float* Wq   = (const float*)d_in[5];
  const float* bq   = (const float*)d_in[6];
  const float* Wk   = (const float*)d_in[7];
  const float* bk   = (const float*)d_in[8];
  const float* Wv   = (const float*)d_in[9];
  const float* bv   = (const float*)d_in[10];
  const float* Wo   = (const float*)d_in[11];
  const float* bo   = (const float*)d_in[12];
  const float* centers = (const float*)d_in[13];
  const float* widths  = (const float*)d_in[14];
  const float* geom_w  = (const float*)d_in[15];
  const float* geom_b  = (const float*)d_in[16];
  const float* cq_w = (const float*)d_in[17];
  const float* cq_b = (const float*)d_in[18];
  const float* ck_w = (const float*)d_in[19];
  const float* ck_b = (const float*)d_in[20];
  const float* cv_w = (const float*)d_in[21];
  const float* cv_b = (const float*)d_in[22];
  const float* w1m  = (const float*)d_in[23];
  const float* b1m  = (const float*)d_in[24];
  const float* w2m  = (const float*)d_in[25];
  const float* b2m  = (const float*)d_in[26];
  const float* fw1  = (const float*)d_in[27];
  const float* fb1  = (const float*)d_in[28];
  const float* fw2  = (const float*)d_in[29];
  const float* fb2  = (const float*)d_in[30];
  const float* g1   = (const float*)d_in[31];
  const float* be1  = (const float*)d_in[32];
  const float* g2   = (const float*)d_in[33];
  const float* be2  = (const float*)d_in[34];

  float* ws = (float*)d_ws;
  float* A_sc  = ws + 0;        // 2048
  float* sb    = ws + 2048;     // 64
  float* M     = ws + 2112;     // 256*336 = 86016
  float* vbias = ws + 88128;    // 352
  float* MM    = ws + 88480;    // 256*336 = 86016
  float* vb2   = ws + 174496;   // 352
  float* CV1   = ws + 174848;   // 320*256 = 81920
  float* cb1   = ws + 256768;   // 256
  unsigned short* W1t = (unsigned short*)(ws + 257024);   // 512*256 bf16
  unsigned short* W2t = (unsigned short*)(ws + 322560);   // 256*512 bf16
  float* updw = ws + 388096;                              // 8192*256 f32
  // total ws use: ~10 MB

  // scratch inside d_out (134 MB, fully overwritten by kf at the end):
  float* outp = (float*)d_out;
  float* yf  = outp;               // 8192*8*256 f32 = 16,777,216 floats
  float* T   = outp + 16777216;    // 8192*336 f32   =  2,752,512
  float* BPf = outp + 19529728;    // 8192*256 f32   =  2,097,152
  float* zf  = outp + 21626880;    // 8192*320 f32   =  2,621,440  (ends 24,248,320 < 33,554,432)

  k0_prep<<<dim3(1), dim3(256), 0, stream>>>(seed, Wq, bq, Wk, bk, A_sc, sb);
  kp1<<<dim3(256), dim3(352), 0, stream>>>(cq_w, cq_b, ck_w, ck_b, M, vbias);
  kp2<<<dim3(257), dim3(352), 0, stream>>>(Wo, bo, M, vbias, MM, vb2);
  kp3<<<dim3(321), dim3(256), 0, stream>>>(cv_w, cv_b, w1m, b1m, CV1, cb1);
  kcast<<<dim3(768), dim3(256), 0, stream>>>(fw1, fw2, W1t, W2t);
  kg1<<<dim3(2048), dim3(256), 0, stream>>>(x, A_sc, sb, yf);
  g2k<<<dim3(2048), dim3(256), 0, stream>>>(yf, Wv, bv, BPf);
  gb1<<<dim3(1024), dim3(384), 0, stream>>>(BPf, MM, vb2, T);
  kg3<<<dim3(2048), dim3(256), 0, stream>>>(x, pos, T, centers, widths, geom_w, geom_b, zf);
  gb2<<<dim3(1024), dim3(256), 0, stream>>>(zf, CV1, cb1, w2m, b2m, updw);
  kf<<<dim3(2048), dim3(512), 0, stream>>>(x, updw, W1t, W2t, fb1, fb2, g1, be1, g2, be2, outp);
}